// Round 15
// baseline (301.174 us; speedup 1.0000x reference)
//
#include <hip/hip_runtime.h>

// ---------------------------------------------------------------------------
// Fused MHA forward on MI355X (gfx950), bf16 MFMA path, round 19.
// B=8, N=1024, C=1024, H=16, D=64.  M = B*N = 8192.
// ws (64 MB): [0,16M) xb then ob; [16,32M) qb then woutb; [32,48M) kb;
//             [48,64M) vbT.   d_out: [0,6M) winb (dead before out_gemm).
// NEW vs round 18 (assemble best-measured config, delete overhead):
//  * qkv: back to R13 128-tile triple-buffered counted-vmcnt kernel (the
//    277.3us run's component; 256x128 variant was ~equal-or-worse at
//    1 blk/CU). q scale back to 0.125 (e-domain).
//  * scale_f32 DELETED: attn uses raw mask as MFMA C-operand + __expf
//    (v_mul log2e + v_exp = identical VALU to exp2+prescaled mask, minus
//    the 8MB scale pass and its launch gap).
//  * attn occupancy 3 -> 5 blocks/CU (LDS exactly 32KB, VGPR 60 -> free).
// ---------------------------------------------------------------------------

typedef __bf16 bf16x8 __attribute__((ext_vector_type(8)));
typedef float f32x4 __attribute__((ext_vector_type(4)));
typedef float f32x16 __attribute__((ext_vector_type(16)));
typedef unsigned short us4v __attribute__((ext_vector_type(4)));
typedef unsigned int u32x4 __attribute__((ext_vector_type(4)));

#define MFMA16 __builtin_amdgcn_mfma_f32_16x16x32_bf16
#define MFMA32 __builtin_amdgcn_mfma_f32_32x32x16_bf16

__device__ __forceinline__ unsigned short f2bf(float f) {
    return __builtin_bit_cast(unsigned short, (__bf16)f);   // native cvt, RNE
}

__device__ __forceinline__ us4v cvt4(float4 v) {
    us4v r;
    r.x = f2bf(v.x); r.y = f2bf(v.y); r.z = f2bf(v.z); r.w = f2bf(v.w);
    return r;
}

__device__ __forceinline__ unsigned cvtpk(float lo, float hi) {
    unsigned r;
    asm volatile("v_cvt_pk_bf16_f32 %0, %1, %2" : "=v"(r) : "v"(lo), "v"(hi));
    return r;
}

// async global->LDS, 16 B per lane; LDS dest = wave-uniform base + lane*16
__device__ __forceinline__ void gl16(const unsigned short* g, unsigned short* l) {
    __builtin_amdgcn_global_load_lds(
        (const __attribute__((address_space(1))) unsigned*)g,
        (__attribute__((address_space(3))) unsigned*)l, 16, 0, 0);
}

// ---------------------------------------------------------------------------
// Kernel 0: fp32 -> bf16 convert (one float4 per thread)
// ---------------------------------------------------------------------------
__global__ __launch_bounds__(256)
void cvt_bf16(const float* __restrict__ src, unsigned short* __restrict__ dst,
              int n4) {
    const int i = blockIdx.x * 256 + threadIdx.x;
    if (i < n4) {
        float4 v = ((const float4*)src)[i];
        ((us4v*)dst)[i] = cvt4(v);
    }
}

// ---------------------------------------------------------------------------
// Kernel 1: qkv = xb @ winb^T + b_in -> q (x0.125), k in (B,H,N,D) bf16,
//           V written directly transposed as vbT (B,H,D,N) bf16.
// Triple-buffered counted-vmcnt pipeline (R13; the 277us-run component).
// ---------------------------------------------------------------------------
__global__ __launch_bounds__(256, 3)
void qkv_gemm(const unsigned short* __restrict__ xb,   // (8192,1024) bf16
              const unsigned short* __restrict__ wb,   // (3072,1024) bf16
              const float* __restrict__ bias,
              unsigned short* __restrict__ qb, unsigned short* __restrict__ kb,
              unsigned short* __restrict__ vbT)
{
    __shared__ unsigned short lsa[3][128 * 32];
    __shared__ unsigned short lsb[3][128 * 32];
    const int tid  = threadIdx.x;
    const int wave = tid >> 6, lane = tid & 63;
    const int quad = lane >> 4, l15 = lane & 15;
    const int rch = (quad ^ ((l15 >> 1) & 3)) * 8;   // swizzled read chunk
    const int m0 = blockIdx.x * 128, n0 = blockIdx.y * 128;
    const int wm = (wave & 1) * 64, wn = (wave >> 1) * 64;

    const int srow = wave * 32 + (lane >> 2);
    const int scol = ((lane & 3) ^ ((lane >> 3) & 3)) * 8;   // swizzled stage
    const unsigned short* ga = xb + (size_t)(m0 + srow) * 1024 + scol;
    const unsigned short* gb = wb + (size_t)(n0 + srow) * 1024 + scol;
    const int so0 = (wave * 32) * 32;          // stage offsets within a buffer
    const int so1 = (wave * 32 + 16) * 32;

    f32x4 acc[4][4];
#pragma unroll
    for (int i = 0; i < 4; ++i)
#pragma unroll
        for (int j = 0; j < 4; ++j) acc[i][j] = (f32x4){0.f, 0.f, 0.f, 0.f};

    gl16(ga, &lsa[0][so0]);
    gl16(ga + 16 * 1024, &lsa[0][so1]);
    gl16(gb, &lsb[0][so0]);
    gl16(gb + 16 * 1024, &lsb[0][so1]);
    gl16(ga + 32, &lsa[1][so0]);
    gl16(ga + 16 * 1024 + 32, &lsa[1][so1]);
    gl16(gb + 32, &lsb[1][so0]);
    gl16(gb + 16 * 1024 + 32, &lsb[1][so1]);

    for (int kt = 0; kt < 32; ++kt) {
        const int cb = kt % 3;
        if (kt < 30) {                         // stage kt+2 (distance 2)
            const int k0 = (kt + 2) * 32;
            const int sb = (kt + 2) % 3;
            gl16(ga + k0, &lsa[sb][so0]);
            gl16(ga + 16 * 1024 + k0, &lsa[sb][so1]);
            gl16(gb + k0, &lsb[sb][so0]);
            gl16(gb + 16 * 1024 + k0, &lsb[sb][so1]);
            asm volatile("s_waitcnt vmcnt(8)" ::: "memory");
        } else if (kt == 30) {
            asm volatile("s_waitcnt vmcnt(4)" ::: "memory");
        } else {
            asm volatile("s_waitcnt vmcnt(0)" ::: "memory");
        }
        __builtin_amdgcn_s_barrier();

        const unsigned short* pa = lsa[cb];
        const unsigned short* pb = lsb[cb];
        bf16x8 af[4], bfr[4];
#pragma unroll
        for (int i = 0; i < 4; ++i)
            af[i] = *(const bf16x8*)&pa[(wm + i * 16 + l15) * 32 + rch];
#pragma unroll
        for (int j = 0; j < 4; ++j)
            bfr[j] = *(const bf16x8*)&pb[(wn + j * 16 + l15) * 32 + rch];
#pragma unroll
        for (int i = 0; i < 4; ++i)
#pragma unroll
            for (int j = 0; j < 4; ++j)
                acc[i][j] = MFMA16(af[i], bfr[j], acc[i][j], 0, 0, 0);

        asm volatile("s_waitcnt lgkmcnt(0)" ::: "memory");
        __builtin_amdgcn_sched_barrier(0);
        __builtin_amdgcn_s_barrier();
    }

    const int which = n0 >> 10;
    if (which == 2) {
        // V: write transposed (bh, d, seq); (i,r) axis is seq -> pack 4 bf16.
#pragma unroll
        for (int j = 0; j < 4; ++j) {
            const int n = n0 + wn + j * 16 + l15;
            const int c = n & 1023;
            const int h = c >> 6, d = c & 63;
            const float bv = bias[n];
#pragma unroll
            for (int i = 0; i < 4; ++i) {
                const int m = m0 + wm + i * 16 + quad * 4;   // r=0 row
                const int b = m >> 10, s = m & 1023;
                us4v pk;
#pragma unroll
                for (int r = 0; r < 4; ++r) pk[r] = f2bf(acc[i][j][r] + bv);
                *(us4v*)&vbT[(size_t)((b * 16 + h) * 64 + d) * 1024 + s] = pk;
            }
        }
    } else {
        unsigned short* __restrict__ dst = (which == 0) ? qb : kb;
        const float sc = (which == 0) ? 0.125f : 1.0f;   // q / sqrt(64)
#pragma unroll
        for (int j = 0; j < 4; ++j) {
            const int n = n0 + wn + j * 16 + l15;
            const int c = n & 1023;
            const int h = c >> 6, d = c & 63;
            const float bv = bias[n];
#pragma unroll
            for (int i = 0; i < 4; ++i)
#pragma unroll
                for (int r = 0; r < 4; ++r) {
                    const int m = m0 + wm + i * 16 + quad * 4 + r;
                    const int b = m >> 10, s = m & 1023;
                    const float v = (acc[i][j][r] + bv) * sc;
                    dst[(size_t)((b * 16 + h) * 1024 + s) * 64 + d] = f2bf(v);
                }
        }
    }
}

// ---------------------------------------------------------------------------
// Kernel 2: flash attention, 32x32 MFMA, in-register P (T12).
//   Raw mask as MFMA C-operand; p = __expf(s) (mul+exp, same VALU as the
//   old exp2+prescaled-mask but no scale pass). 5 blocks/CU (32KB LDS).
// ---------------------------------------------------------------------------
__global__ __launch_bounds__(256, 5)
void attn_kernel(const unsigned short* __restrict__ qb,
                 const unsigned short* __restrict__ kb,
                 const unsigned short* __restrict__ vbT,  // (bh, d, n)
                 const float* __restrict__ mask,          // raw (1024,1024)
                 unsigned short* __restrict__ ob)   // (B, N, C) bf16
{
    __shared__ unsigned short lsk[2][2][64 * 32];  // [buf][d-half][key*32]
    __shared__ unsigned short lsv[2][2][64 * 32];  // [buf][key-half][d*32]
    const int tid  = threadIdx.x;
    const int wave = tid >> 6, lane = tid & 63;
    const int r5 = lane & 31, hl = lane >> 5;
    const int rs = ((r5 >> 1) ^ (r5 >> 3)) & 3;    // read-chunk swizzle
    const int p  = blockIdx.x;
    const int lg = (p & 7) * 128 + (p >> 3);       // XCD swizzle (bijective)
    const int bh = lg >> 3;                        // b*16+h
    const int q0 = (lg & 7) * 128;
    const int b = bh >> 4, head = bh & 15;

    const unsigned short* __restrict__ kbase = kb + (size_t)bh * 65536;
    const unsigned short* __restrict__ vtb  = vbT + (size_t)bh * 65536;

    // stage: row r = wave*16 + lane>>2; S(r)=((r>>1)^(r>>3))&3 via lane bits
    const int scol =
        ((lane & 3) ^ ((lane >> 3) & 3) ^ ((2 * wave + (lane >> 5)) & 3)) * 8;
    const unsigned short* gk = kbase + (size_t)(wave * 16 + (lane >> 2)) * 64
                                     + scol;
    const unsigned short* gv = vtb + (size_t)(wave * 16 + (lane >> 2)) * 1024
                                   + scol;
    const int so = (wave * 16) * 32;             // stage offset within a half

    // Q fragments (B-operand: n=q=l&31, k=d=kk*16+8*hl+j), q pre-scaled
    const int q = q0 + wave * 32 + r5;
    bf16x8 bq[4];
    {
        const unsigned short* qrow = qb + (size_t)(bh * 1024 + q) * 64;
#pragma unroll
        for (int kk = 0; kk < 4; ++kk)
            bq[kk] = *(const bf16x8*)(qrow + kk * 16 + hl * 8);
    }

    float lsum = 0.f;
    f32x16 acc[2];                 // [dt]: O^T[d=32dt+(r&3)+8(r>>2)+4hl][q]
#pragma unroll
    for (int dt = 0; dt < 2; ++dt)
#pragma unroll
        for (int r = 0; r < 16; ++r) acc[dt][r] = 0.f;

    const float* __restrict__ mq = mask + (size_t)q * 1024;

    // prologue: stage tile 0 into buf 0
    gl16(gk, &lsk[0][0][so]);
    gl16(gk + 32, &lsk[0][1][so]);
    gl16(gv, &lsv[0][0][so]);
    gl16(gv + 32, &lsv[0][1][so]);
    __syncthreads();

    int buf = 0;
    for (int kt = 0; kt < 16; ++kt) {
        // masks for CURRENT tile (oldest vmem -> QK's wait leaves the
        // younger prefetch gl16s in flight)
        f32x16 msk[2];
#pragma unroll
        for (int t32 = 0; t32 < 2; ++t32)
#pragma unroll
            for (int oct = 0; oct < 4; ++oct) {
                const float4 mv = *(const float4*)
                    &mq[kt * 64 + t32 * 32 + oct * 8 + hl * 4];
                msk[t32][4 * oct + 0] = mv.x;
                msk[t32][4 * oct + 1] = mv.y;
                msk[t32][4 * oct + 2] = mv.z;
                msk[t32][4 * oct + 3] = mv.w;
            }
        __builtin_amdgcn_sched_barrier(0);     // keep mask loads oldest
        if (kt < 15) {                         // stage next tile early
            gl16(gk + (size_t)(kt + 1) * 4096, &lsk[buf ^ 1][0][so]);
            gl16(gk + (size_t)(kt + 1) * 4096 + 32, &lsk[buf ^ 1][1][so]);
            gl16(gv + (size_t)(kt + 1) * 64, &lsv[buf ^ 1][0][so]);
            gl16(gv + (size_t)(kt + 1) * 64 + 32, &lsv[buf ^ 1][1][so]);
        }

#pragma unroll
        for (int t32 = 0; t32 < 2; ++t32) {
            // S^T = K Q^T + mask (C operand), 32 keys x 32 q, 4x K=16
            f32x16 s = msk[t32];
            __builtin_amdgcn_s_setprio(1);
#pragma unroll
            for (int kk = 0; kk < 4; ++kk) {
                const unsigned short* kp = lsk[buf][kk >> 1];
                const int c4 = 2 * (kk & 1) + hl;
                const bf16x8 ka = *(const bf16x8*)
                    &kp[(t32 * 32 + r5) * 32 + ((c4 ^ rs) * 8)];
                s = MFMA32(ka, bq[kk], s, 0, 0, 0);
            }
            __builtin_amdgcn_s_setprio(0);

            // softmax: p = exp(s); pack + permlane32_swap -> B-frags
            float pv[16];
            float ts = 0.f;
#pragma unroll
            for (int r = 0; r < 16; ++r) {
                pv[r] = __expf(s[r]);
                ts += pv[r];
            }
            lsum += ts;

            bf16x8 pfr[2];
#pragma unroll
            for (int cl = 0; cl < 2; ++cl) {
                unsigned xa = cvtpk(pv[8 * cl + 0], pv[8 * cl + 1]);
                unsigned xb = cvtpk(pv[8 * cl + 2], pv[8 * cl + 3]);
                unsigned ya = cvtpk(pv[8 * cl + 4], pv[8 * cl + 5]);
                unsigned yb = cvtpk(pv[8 * cl + 6], pv[8 * cl + 7]);
                asm volatile("v_permlane32_swap_b32 %0, %1"
                             : "+v"(xa), "+v"(ya));
                asm volatile("v_permlane32_swap_b32 %0, %1"
                             : "+v"(xb), "+v"(yb));
                const u32x4 t = {xa, xb, ya, yb};
                pfr[cl] = __builtin_bit_cast(bf16x8, t);
            }

            // O^T += V^T x P^T  (A = V^T frag, B = P frag), K=16 per chunk
            __builtin_amdgcn_s_setprio(1);
#pragma unroll
            for (int cl = 0; cl < 2; ++cl) {
                const int cg = t32 * 2 + cl;
                const unsigned short* vp = lsv[buf][cg >> 1];
                const int c4v = 2 * (cg & 1) + hl;
                const int voff = (c4v ^ rs) * 8;
#pragma unroll
                for (int dt = 0; dt < 2; ++dt) {
                    const bf16x8 va = *(const bf16x8*)
                        &vp[(dt * 32 + r5) * 32 + voff];
                    acc[dt] = MFMA32(va, pfr[cl], acc[dt], 0, 0, 0);
                }
            }
            __builtin_amdgcn_s_setprio(0);
        }

        __syncthreads();                       // drain stage + protect bufs
        buf ^= 1;
    }

    // lane covers keys with (key&7)>>2 == hl; partner lane has the rest
    lsum += __shfl_xor(lsum, 32, 64);
    const float inv = 1.0f / lsum;

    unsigned short* orow =
        ob + (size_t)(b * 1024 + q) * 1024 + head * 64;
#pragma unroll
    for (int dt = 0; dt < 2; ++dt)
#pragma unroll
        for (int oct = 0; oct < 4; ++oct) {
            us4v o;
#pragma unroll
            for (int r = 0; r < 4; ++r)
                o[r] = f2bf(acc[dt][4 * oct + r] * inv);
            *(us4v*)&orow[dt * 32 + oct * 8 + hl * 4] = o;
        }
}

// ---------------------------------------------------------------------------
// Kernel 3: out = ob(bf16) @ woutb^T + out_b, fp32 to d_out (R13 unchanged).
// ---------------------------------------------------------------------------
__global__ __launch_bounds__(256, 3)
void out_gemm(const unsigned short* __restrict__ a,   // (8192,1024) bf16
              const unsigned short* __restrict__ wb,  // (1024,1024) bf16
              const float* __restrict__ bias, float* __restrict__ out)
{
    __shared__ unsigned short lsa[3][128 * 32];
    __shared__ unsigned short lsb[3][128 * 32];
    const int tid  = threadIdx.x;
    const int wave = tid >> 6, lane = tid & 63;
    const int quad = lane >> 4, l15 = lane & 15;
    const int rch = (quad ^ ((l15 >> 1) & 3)) * 8;
    const int m0 = blockIdx.x * 128, n0 = blockIdx.y * 128;
    const int wm = (wave & 1) * 64, wn = (wave >> 1) * 64;

    const int srow = wave * 32 + (lane >> 2);
    const int scol = ((lane & 3) ^ ((lane >> 3) & 3)) * 8;
    const unsigned short* ga = a + (size_t)(m0 + srow) * 1024 + scol;
    const unsigned short* gb = wb + (size_t)(n0 + srow) * 1024 + scol;
    const int so0 = (wave * 32) * 32;
    const int so1 = (wave * 32 + 16) * 32;

    f32x4 acc[4][4];
#pragma unroll
    for (int i = 0; i < 4; ++i)
#pragma unroll
        for (int j = 0; j < 4; ++j) acc[i][j] = (f32x4){0.f, 0.f, 0.f, 0.f};

    gl16(ga, &lsa[0][so0]);
    gl16(ga + 16 * 1024, &lsa[0][so1]);
    gl16(gb, &lsb[0][so0]);
    gl16(gb + 16 * 1024, &lsb[0][so1]);
    gl16(ga + 32, &lsa[1][so0]);
    gl16(ga + 16 * 1024 + 32, &lsa[1][so1]);
    gl16(gb + 32, &lsb[1][so0]);
    gl16(gb + 16 * 1024 + 32, &lsb[1][so1]);

    for (int kt = 0; kt < 32; ++kt) {
        const int cb = kt % 3;
        if (kt < 30) {
            const int k0 = (kt + 2) * 32;
            const int sb = (kt + 2) % 3;
            gl16(ga + k0, &lsa[sb][so0]);
            gl16(ga + 16 * 1024 + k0, &lsa[sb][so1]);
            gl16(gb + k0, &lsb[sb][so0]);
            gl16(gb + 16 * 1024 + k0, &lsb[sb][so1]);
            asm volatile("s_waitcnt vmcnt(8)" ::: "memory");
        } else if (kt == 30) {
            asm volatile("s_waitcnt vmcnt(4)" ::: "memory");
        } else {
            asm volatile("s_waitcnt vmcnt(0)" ::: "memory");
        }
        __builtin_amdgcn_s_barrier();

        const unsigned short* pa = lsa[cb];
        const unsigned short* pb = lsb[cb];
        bf16x8 af[4], bfr[4];
#pragma unroll
        for (int i = 0; i < 4; ++i)
            af[i] = *(const bf16x8*)&pa[(wm + i * 16 + l15) * 32 + rch];
#pragma unroll
        for (int j = 0; j < 4; ++j)
            bfr[j] = *(const bf16x8*)&pb[(wn + j * 16 + l15) * 32 + rch];
#pragma unroll
        for (int i = 0; i < 4; ++i)
#pragma unroll
            for (int j = 0; j < 4; ++j)
                acc[i][j] = MFMA16(af[i], bfr[j], acc[i][j], 0, 0, 0);

        asm volatile("s_waitcnt lgkmcnt(0)" ::: "memory");
        __builtin_amdgcn_sched_barrier(0);
        __builtin_amdgcn_s_barrier();
    }

#pragma unroll
    for (int j = 0; j < 4; ++j) {
        const int n = n0 + wn + j * 16 + l15;
        const float bv = bias[n];
#pragma unroll
        for (int i = 0; i < 4; ++i)
#pragma unroll
            for (int r = 0; r < 4; ++r) {
                const int m = m0 + wm + i * 16 + quad * 4 + r;
                out[(size_t)m * 1024 + n] = acc[i][j][r] + bv;
            }
    }
}

// ---------------------------------------------------------------------------
extern "C" void kernel_launch(void* const* d_in, const int* in_sizes, int n_in,
                              void* d_out, int out_size, void* d_ws, size_t ws_size,
                              hipStream_t stream) {
    const float* x    = (const float*)d_in[0];   // (8, 1024, 1024)
    const float* mask = (const float*)d_in[1];   // (1024, 1024)
    const float* win  = (const float*)d_in[2];   // (3072, 1024)
    const float* bin  = (const float*)d_in[3];   // (3072)
    const float* wout = (const float*)d_in[4];   // (1024, 1024)
    const float* bout = (const float*)d_in[5];   // (1024)
    float* out = (float*)d_out;                  // (8, 1024, 1024)

    char* ws = (char*)d_ws;
    unsigned short* xb = (unsigned short*)(ws);
    unsigned short* ob = (unsigned short*)(ws);                       // overlays xb
    unsigned short* qb = (unsigned short*)(ws + (size_t)(16 << 20));
    unsigned short* kb = (unsigned short*)(ws + (size_t)(32 << 20));
    unsigned short* vbT = (unsigned short*)(ws + (size_t)(48 << 20));
    unsigned short* winb  = (unsigned short*)d_out;                   // [0, 6M)
    unsigned short* woutb = qb;   // overlays qb AFTER attn (qb dead) — no race

    cvt_bf16<<<dim3(8192), 256, 0, stream>>>(x, xb, 8 * 1024 * 1024 / 4);
    cvt_bf16<<<dim3(3072), 256, 0, stream>>>(win, winb, 3 * 1024 * 1024 / 4);
    qkv_gemm<<<dim3(64, 24), 256, 0, stream>>>(xb, winb, bin, qb, kb, vbT);
    attn_kernel<<<dim3(1024), 256, 0, stream>>>(qb, kb, vbT, mask, ob);
    cvt_bf16<<<dim3(1024), 256, 0, stream>>>(wout, woutb, 1024 * 1024 / 4);
    out_gemm<<<dim3(64, 8), 256, 0, stream>>>(ob, woutb, bout, out);
}

// Round 16
// 279.068 us; speedup vs baseline: 1.0792x; 1.0792x over previous
//
#include <hip/hip_runtime.h>

// ---------------------------------------------------------------------------
// Fused MHA forward on MI355X (gfx950), bf16 MFMA path, round 20.
// B=8, N=1024, C=1024, H=16, D=64.  M = B*N = 8192.
// ws (64 MB): [0,16M) xb then ob; [16,32M) qb then woutb; [32,48M) kb;
//             [48,64M) vbT.   d_out: [0,6M) winb (dead before out_gemm).
// NEW vs round 19 (ONE token): attn __launch_bounds__(256,5) -> (256,3).
//  * R19's (256,5) capped the allocator: VGPR 60->48 with scratch spills
//    (WRITE_SIZE 16->50 MB/dispatch) -> attn 96->115us, VALUBusy 38->19%.
//    (256,3) restores the verified 95.7us allocation. Kept from R19:
//    scale_f32 deleted (raw mask as MFMA C-operand + __expf), R13 128-tile
//    qkv, R13 out_gemm.
// ---------------------------------------------------------------------------

typedef __bf16 bf16x8 __attribute__((ext_vector_type(8)));
typedef float f32x4 __attribute__((ext_vector_type(4)));
typedef float f32x16 __attribute__((ext_vector_type(16)));
typedef unsigned short us4v __attribute__((ext_vector_type(4)));
typedef unsigned int u32x4 __attribute__((ext_vector_type(4)));

#define MFMA16 __builtin_amdgcn_mfma_f32_16x16x32_bf16
#define MFMA32 __builtin_amdgcn_mfma_f32_32x32x16_bf16

__device__ __forceinline__ unsigned short f2bf(float f) {
    return __builtin_bit_cast(unsigned short, (__bf16)f);   // native cvt, RNE
}

__device__ __forceinline__ us4v cvt4(float4 v) {
    us4v r;
    r.x = f2bf(v.x); r.y = f2bf(v.y); r.z = f2bf(v.z); r.w = f2bf(v.w);
    return r;
}

__device__ __forceinline__ unsigned cvtpk(float lo, float hi) {
    unsigned r;
    asm volatile("v_cvt_pk_bf16_f32 %0, %1, %2" : "=v"(r) : "v"(lo), "v"(hi));
    return r;
}

// async global->LDS, 16 B per lane; LDS dest = wave-uniform base + lane*16
__device__ __forceinline__ void gl16(const unsigned short* g, unsigned short* l) {
    __builtin_amdgcn_global_load_lds(
        (const __attribute__((address_space(1))) unsigned*)g,
        (__attribute__((address_space(3))) unsigned*)l, 16, 0, 0);
}

// ---------------------------------------------------------------------------
// Kernel 0: fp32 -> bf16 convert (one float4 per thread)
// ---------------------------------------------------------------------------
__global__ __launch_bounds__(256)
void cvt_bf16(const float* __restrict__ src, unsigned short* __restrict__ dst,
              int n4) {
    const int i = blockIdx.x * 256 + threadIdx.x;
    if (i < n4) {
        float4 v = ((const float4*)src)[i];
        ((us4v*)dst)[i] = cvt4(v);
    }
}

// ---------------------------------------------------------------------------
// Kernel 1: qkv = xb @ winb^T + b_in -> q (x0.125), k in (B,H,N,D) bf16,
//           V written directly transposed as vbT (B,H,D,N) bf16.
// Triple-buffered counted-vmcnt pipeline (R13; the 277us-run component).
// ---------------------------------------------------------------------------
__global__ __launch_bounds__(256, 3)
void qkv_gemm(const unsigned short* __restrict__ xb,   // (8192,1024) bf16
              const unsigned short* __restrict__ wb,   // (3072,1024) bf16
              const float* __restrict__ bias,
              unsigned short* __restrict__ qb, unsigned short* __restrict__ kb,
              unsigned short* __restrict__ vbT)
{
    __shared__ unsigned short lsa[3][128 * 32];
    __shared__ unsigned short lsb[3][128 * 32];
    const int tid  = threadIdx.x;
    const int wave = tid >> 6, lane = tid & 63;
    const int quad = lane >> 4, l15 = lane & 15;
    const int rch = (quad ^ ((l15 >> 1) & 3)) * 8;   // swizzled read chunk
    const int m0 = blockIdx.x * 128, n0 = blockIdx.y * 128;
    const int wm = (wave & 1) * 64, wn = (wave >> 1) * 64;

    const int srow = wave * 32 + (lane >> 2);
    const int scol = ((lane & 3) ^ ((lane >> 3) & 3)) * 8;   // swizzled stage
    const unsigned short* ga = xb + (size_t)(m0 + srow) * 1024 + scol;
    const unsigned short* gb = wb + (size_t)(n0 + srow) * 1024 + scol;
    const int so0 = (wave * 32) * 32;          // stage offsets within a buffer
    const int so1 = (wave * 32 + 16) * 32;

    f32x4 acc[4][4];
#pragma unroll
    for (int i = 0; i < 4; ++i)
#pragma unroll
        for (int j = 0; j < 4; ++j) acc[i][j] = (f32x4){0.f, 0.f, 0.f, 0.f};

    gl16(ga, &lsa[0][so0]);
    gl16(ga + 16 * 1024, &lsa[0][so1]);
    gl16(gb, &lsb[0][so0]);
    gl16(gb + 16 * 1024, &lsb[0][so1]);
    gl16(ga + 32, &lsa[1][so0]);
    gl16(ga + 16 * 1024 + 32, &lsa[1][so1]);
    gl16(gb + 32, &lsb[1][so0]);
    gl16(gb + 16 * 1024 + 32, &lsb[1][so1]);

    for (int kt = 0; kt < 32; ++kt) {
        const int cb = kt % 3;
        if (kt < 30) {                         // stage kt+2 (distance 2)
            const int k0 = (kt + 2) * 32;
            const int sb = (kt + 2) % 3;
            gl16(ga + k0, &lsa[sb][so0]);
            gl16(ga + 16 * 1024 + k0, &lsa[sb][so1]);
            gl16(gb + k0, &lsb[sb][so0]);
            gl16(gb + 16 * 1024 + k0, &lsb[sb][so1]);
            asm volatile("s_waitcnt vmcnt(8)" ::: "memory");
        } else if (kt == 30) {
            asm volatile("s_waitcnt vmcnt(4)" ::: "memory");
        } else {
            asm volatile("s_waitcnt vmcnt(0)" ::: "memory");
        }
        __builtin_amdgcn_s_barrier();

        const unsigned short* pa = lsa[cb];
        const unsigned short* pb = lsb[cb];
        bf16x8 af[4], bfr[4];
#pragma unroll
        for (int i = 0; i < 4; ++i)
            af[i] = *(const bf16x8*)&pa[(wm + i * 16 + l15) * 32 + rch];
#pragma unroll
        for (int j = 0; j < 4; ++j)
            bfr[j] = *(const bf16x8*)&pb[(wn + j * 16 + l15) * 32 + rch];
#pragma unroll
        for (int i = 0; i < 4; ++i)
#pragma unroll
            for (int j = 0; j < 4; ++j)
                acc[i][j] = MFMA16(af[i], bfr[j], acc[i][j], 0, 0, 0);

        asm volatile("s_waitcnt lgkmcnt(0)" ::: "memory");
        __builtin_amdgcn_sched_barrier(0);
        __builtin_amdgcn_s_barrier();
    }

    const int which = n0 >> 10;
    if (which == 2) {
        // V: write transposed (bh, d, seq); (i,r) axis is seq -> pack 4 bf16.
#pragma unroll
        for (int j = 0; j < 4; ++j) {
            const int n = n0 + wn + j * 16 + l15;
            const int c = n & 1023;
            const int h = c >> 6, d = c & 63;
            const float bv = bias[n];
#pragma unroll
            for (int i = 0; i < 4; ++i) {
                const int m = m0 + wm + i * 16 + quad * 4;   // r=0 row
                const int b = m >> 10, s = m & 1023;
                us4v pk;
#pragma unroll
                for (int r = 0; r < 4; ++r) pk[r] = f2bf(acc[i][j][r] + bv);
                *(us4v*)&vbT[(size_t)((b * 16 + h) * 64 + d) * 1024 + s] = pk;
            }
        }
    } else {
        unsigned short* __restrict__ dst = (which == 0) ? qb : kb;
        const float sc = (which == 0) ? 0.125f : 1.0f;   // q / sqrt(64)
#pragma unroll
        for (int j = 0; j < 4; ++j) {
            const int n = n0 + wn + j * 16 + l15;
            const int c = n & 1023;
            const int h = c >> 6, d = c & 63;
            const float bv = bias[n];
#pragma unroll
            for (int i = 0; i < 4; ++i)
#pragma unroll
                for (int r = 0; r < 4; ++r) {
                    const int m = m0 + wm + i * 16 + quad * 4 + r;
                    const int b = m >> 10, s = m & 1023;
                    const float v = (acc[i][j][r] + bv) * sc;
                    dst[(size_t)((b * 16 + h) * 1024 + s) * 64 + d] = f2bf(v);
                }
        }
    }
}

// ---------------------------------------------------------------------------
// Kernel 2: flash attention, 32x32 MFMA, in-register P (T12).
//   Raw mask as MFMA C-operand; p = __expf(s). launch_bounds(256,3)
//   (R16's verified allocation: 60 VGPR, no spill).
// ---------------------------------------------------------------------------
__global__ __launch_bounds__(256, 3)
void attn_kernel(const unsigned short* __restrict__ qb,
                 const unsigned short* __restrict__ kb,
                 const unsigned short* __restrict__ vbT,  // (bh, d, n)
                 const float* __restrict__ mask,          // raw (1024,1024)
                 unsigned short* __restrict__ ob)   // (B, N, C) bf16
{
    __shared__ unsigned short lsk[2][2][64 * 32];  // [buf][d-half][key*32]
    __shared__ unsigned short lsv[2][2][64 * 32];  // [buf][key-half][d*32]
    const int tid  = threadIdx.x;
    const int wave = tid >> 6, lane = tid & 63;
    const int r5 = lane & 31, hl = lane >> 5;
    const int rs = ((r5 >> 1) ^ (r5 >> 3)) & 3;    // read-chunk swizzle
    const int p  = blockIdx.x;
    const int lg = (p & 7) * 128 + (p >> 3);       // XCD swizzle (bijective)
    const int bh = lg >> 3;                        // b*16+h
    const int q0 = (lg & 7) * 128;
    const int b = bh >> 4, head = bh & 15;

    const unsigned short* __restrict__ kbase = kb + (size_t)bh * 65536;
    const unsigned short* __restrict__ vtb  = vbT + (size_t)bh * 65536;

    // stage: row r = wave*16 + lane>>2; S(r)=((r>>1)^(r>>3))&3 via lane bits
    const int scol =
        ((lane & 3) ^ ((lane >> 3) & 3) ^ ((2 * wave + (lane >> 5)) & 3)) * 8;
    const unsigned short* gk = kbase + (size_t)(wave * 16 + (lane >> 2)) * 64
                                     + scol;
    const unsigned short* gv = vtb + (size_t)(wave * 16 + (lane >> 2)) * 1024
                                   + scol;
    const int so = (wave * 16) * 32;             // stage offset within a half

    // Q fragments (B-operand: n=q=l&31, k=d=kk*16+8*hl+j), q pre-scaled
    const int q = q0 + wave * 32 + r5;
    bf16x8 bq[4];
    {
        const unsigned short* qrow = qb + (size_t)(bh * 1024 + q) * 64;
#pragma unroll
        for (int kk = 0; kk < 4; ++kk)
            bq[kk] = *(const bf16x8*)(qrow + kk * 16 + hl * 8);
    }

    float lsum = 0.f;
    f32x16 acc[2];                 // [dt]: O^T[d=32dt+(r&3)+8(r>>2)+4hl][q]
#pragma unroll
    for (int dt = 0; dt < 2; ++dt)
#pragma unroll
        for (int r = 0; r < 16; ++r) acc[dt][r] = 0.f;

    const float* __restrict__ mq = mask + (size_t)q * 1024;

    // prologue: stage tile 0 into buf 0
    gl16(gk, &lsk[0][0][so]);
    gl16(gk + 32, &lsk[0][1][so]);
    gl16(gv, &lsv[0][0][so]);
    gl16(gv + 32, &lsv[0][1][so]);
    __syncthreads();

    int buf = 0;
    for (int kt = 0; kt < 16; ++kt) {
        // masks for CURRENT tile (oldest vmem -> QK's wait leaves the
        // younger prefetch gl16s in flight)
        f32x16 msk[2];
#pragma unroll
        for (int t32 = 0; t32 < 2; ++t32)
#pragma unroll
            for (int oct = 0; oct < 4; ++oct) {
                const float4 mv = *(const float4*)
                    &mq[kt * 64 + t32 * 32 + oct * 8 + hl * 4];
                msk[t32][4 * oct + 0] = mv.x;
                msk[t32][4 * oct + 1] = mv.y;
                msk[t32][4 * oct + 2] = mv.z;
                msk[t32][4 * oct + 3] = mv.w;
            }
        __builtin_amdgcn_sched_barrier(0);     // keep mask loads oldest
        if (kt < 15) {                         // stage next tile early
            gl16(gk + (size_t)(kt + 1) * 4096, &lsk[buf ^ 1][0][so]);
            gl16(gk + (size_t)(kt + 1) * 4096 + 32, &lsk[buf ^ 1][1][so]);
            gl16(gv + (size_t)(kt + 1) * 64, &lsv[buf ^ 1][0][so]);
            gl16(gv + (size_t)(kt + 1) * 64 + 32, &lsv[buf ^ 1][1][so]);
        }

#pragma unroll
        for (int t32 = 0; t32 < 2; ++t32) {
            // S^T = K Q^T + mask (C operand), 32 keys x 32 q, 4x K=16
            f32x16 s = msk[t32];
            __builtin_amdgcn_s_setprio(1);
#pragma unroll
            for (int kk = 0; kk < 4; ++kk) {
                const unsigned short* kp = lsk[buf][kk >> 1];
                const int c4 = 2 * (kk & 1) + hl;
                const bf16x8 ka = *(const bf16x8*)
                    &kp[(t32 * 32 + r5) * 32 + ((c4 ^ rs) * 8)];
                s = MFMA32(ka, bq[kk], s, 0, 0, 0);
            }
            __builtin_amdgcn_s_setprio(0);

            // softmax: p = exp(s); pack + permlane32_swap -> B-frags
            float pv[16];
            float ts = 0.f;
#pragma unroll
            for (int r = 0; r < 16; ++r) {
                pv[r] = __expf(s[r]);
                ts += pv[r];
            }
            lsum += ts;

            bf16x8 pfr[2];
#pragma unroll
            for (int cl = 0; cl < 2; ++cl) {
                unsigned xa = cvtpk(pv[8 * cl + 0], pv[8 * cl + 1]);
                unsigned xb = cvtpk(pv[8 * cl + 2], pv[8 * cl + 3]);
                unsigned ya = cvtpk(pv[8 * cl + 4], pv[8 * cl + 5]);
                unsigned yb = cvtpk(pv[8 * cl + 6], pv[8 * cl + 7]);
                asm volatile("v_permlane32_swap_b32 %0, %1"
                             : "+v"(xa), "+v"(ya));
                asm volatile("v_permlane32_swap_b32 %0, %1"
                             : "+v"(xb), "+v"(yb));
                const u32x4 t = {xa, xb, ya, yb};
                pfr[cl] = __builtin_bit_cast(bf16x8, t);
            }

            // O^T += V^T x P^T  (A = V^T frag, B = P frag), K=16 per chunk
            __builtin_amdgcn_s_setprio(1);
#pragma unroll
            for (int cl = 0; cl < 2; ++cl) {
                const int cg = t32 * 2 + cl;
                const unsigned short* vp = lsv[buf][cg >> 1];
                const int c4v = 2 * (cg & 1) + hl;
                const int voff = (c4v ^ rs) * 8;
#pragma unroll
                for (int dt = 0; dt < 2; ++dt) {
                    const bf16x8 va = *(const bf16x8*)
                        &vp[(dt * 32 + r5) * 32 + voff];
                    acc[dt] = MFMA32(va, pfr[cl], acc[dt], 0, 0, 0);
                }
            }
            __builtin_amdgcn_s_setprio(0);
        }

        __syncthreads();                       // drain stage + protect bufs
        buf ^= 1;
    }

    // lane covers keys with (key&7)>>2 == hl; partner lane has the rest
    lsum += __shfl_xor(lsum, 32, 64);
    const float inv = 1.0f / lsum;

    unsigned short* orow =
        ob + (size_t)(b * 1024 + q) * 1024 + head * 64;
#pragma unroll
    for (int dt = 0; dt < 2; ++dt)
#pragma unroll
        for (int oct = 0; oct < 4; ++oct) {
            us4v o;
#pragma unroll
            for (int r = 0; r < 4; ++r)
                o[r] = f2bf(acc[dt][4 * oct + r] * inv);
            *(us4v*)&orow[dt * 32 + oct * 8 + hl * 4] = o;
        }
}

// ---------------------------------------------------------------------------
// Kernel 3: out = ob(bf16) @ woutb^T + out_b, fp32 to d_out (R13 unchanged).
// ---------------------------------------------------------------------------
__global__ __launch_bounds__(256, 3)
void out_gemm(const unsigned short* __restrict__ a,   // (8192,1024) bf16
              const unsigned short* __restrict__ wb,  // (1024,1024) bf16
              const float* __restrict__ bias, float* __restrict__ out)
{
    __shared__ unsigned short lsa[3][128 * 32];
    __shared__ unsigned short lsb[3][128 * 32];
    const int tid  = threadIdx.x;
    const int wave = tid >> 6, lane = tid & 63;
    const int quad = lane >> 4, l15 = lane & 15;
    const int rch = (quad ^ ((l15 >> 1) & 3)) * 8;
    const int m0 = blockIdx.x * 128, n0 = blockIdx.y * 128;
    const int wm = (wave & 1) * 64, wn = (wave >> 1) * 64;

    const int srow = wave * 32 + (lane >> 2);
    const int scol = ((lane & 3) ^ ((lane >> 3) & 3)) * 8;
    const unsigned short* ga = a + (size_t)(m0 + srow) * 1024 + scol;
    const unsigned short* gb = wb + (size_t)(n0 + srow) * 1024 + scol;
    const int so0 = (wave * 32) * 32;
    const int so1 = (wave * 32 + 16) * 32;

    f32x4 acc[4][4];
#pragma unroll
    for (int i = 0; i < 4; ++i)
#pragma unroll
        for (int j = 0; j < 4; ++j) acc[i][j] = (f32x4){0.f, 0.f, 0.f, 0.f};

    gl16(ga, &lsa[0][so0]);
    gl16(ga + 16 * 1024, &lsa[0][so1]);
    gl16(gb, &lsb[0][so0]);
    gl16(gb + 16 * 1024, &lsb[0][so1]);
    gl16(ga + 32, &lsa[1][so0]);
    gl16(ga + 16 * 1024 + 32, &lsa[1][so1]);
    gl16(gb + 32, &lsb[1][so0]);
    gl16(gb + 16 * 1024 + 32, &lsb[1][so1]);

    for (int kt = 0; kt < 32; ++kt) {
        const int cb = kt % 3;
        if (kt < 30) {
            const int k0 = (kt + 2) * 32;
            const int sb = (kt + 2) % 3;
            gl16(ga + k0, &lsa[sb][so0]);
            gl16(ga + 16 * 1024 + k0, &lsa[sb][so1]);
            gl16(gb + k0, &lsb[sb][so0]);
            gl16(gb + 16 * 1024 + k0, &lsb[sb][so1]);
            asm volatile("s_waitcnt vmcnt(8)" ::: "memory");
        } else if (kt == 30) {
            asm volatile("s_waitcnt vmcnt(4)" ::: "memory");
        } else {
            asm volatile("s_waitcnt vmcnt(0)" ::: "memory");
        }
        __builtin_amdgcn_s_barrier();

        const unsigned short* pa = lsa[cb];
        const unsigned short* pb = lsb[cb];
        bf16x8 af[4], bfr[4];
#pragma unroll
        for (int i = 0; i < 4; ++i)
            af[i] = *(const bf16x8*)&pa[(wm + i * 16 + l15) * 32 + rch];
#pragma unroll
        for (int j = 0; j < 4; ++j)
            bfr[j] = *(const bf16x8*)&pb[(wn + j * 16 + l15) * 32 + rch];
#pragma unroll
        for (int i = 0; i < 4; ++i)
#pragma unroll
            for (int j = 0; j < 4; ++j)
                acc[i][j] = MFMA16(af[i], bfr[j], acc[i][j], 0, 0, 0);

        asm volatile("s_waitcnt lgkmcnt(0)" ::: "memory");
        __builtin_amdgcn_sched_barrier(0);
        __builtin_amdgcn_s_barrier();
    }

#pragma unroll
    for (int j = 0; j < 4; ++j) {
        const int n = n0 + wn + j * 16 + l15;
        const float bv = bias[n];
#pragma unroll
        for (int i = 0; i < 4; ++i)
#pragma unroll
            for (int r = 0; r < 4; ++r) {
                const int m = m0 + wm + i * 16 + quad * 4 + r;
                out[(size_t)m * 1024 + n] = acc[i][j][r] + bv;
            }
    }
}

// ---------------------------------------------------------------------------
extern "C" void kernel_launch(void* const* d_in, const int* in_sizes, int n_in,
                              void* d_out, int out_size, void* d_ws, size_t ws_size,
                              hipStream_t stream) {
    const float* x    = (const float*)d_in[0];   // (8, 1024, 1024)
    const float* mask = (const float*)d_in[1];   // (1024, 1024)
    const float* win  = (const float*)d_in[2];   // (3072, 1024)
    const float* bin  = (const float*)d_in[3];   // (3072)
    const float* wout = (const float*)d_in[4];   // (1024, 1024)
    const float* bout = (const float*)d_in[5];   // (1024)
    float* out = (float*)d_out;                  // (8, 1024, 1024)

    char* ws = (char*)d_ws;
    unsigned short* xb = (unsigned short*)(ws);
    unsigned short* ob = (unsigned short*)(ws);                       // overlays xb
    unsigned short* qb = (unsigned short*)(ws + (size_t)(16 << 20));
    unsigned short* kb = (unsigned short*)(ws + (size_t)(32 << 20));
    unsigned short* vbT = (unsigned short*)(ws + (size_t)(48 << 20));
    unsigned short* winb  = (unsigned short*)d_out;                   // [0, 6M)
    unsigned short* woutb = qb;   // overlays qb AFTER attn (qb dead) — no race

    cvt_bf16<<<dim3(8192), 256, 0, stream>>>(x, xb, 8 * 1024 * 1024 / 4);
    cvt_bf16<<<dim3(3072), 256, 0, stream>>>(win, winb, 3 * 1024 * 1024 / 4);
    qkv_gemm<<<dim3(64, 24), 256, 0, stream>>>(xb, winb, bin, qb, kb, vbT);
    attn_kernel<<<dim3(1024), 256, 0, stream>>>(qb, kb, vbT, mask, ob);
    cvt_bf16<<<dim3(1024), 256, 0, stream>>>(wout, woutb, 1024 * 1024 / 4);
    out_gemm<<<dim3(64, 8), 256, 0, stream>>>(ob, woutb, bout, out);
}

// Round 17
// 277.307 us; speedup vs baseline: 1.0861x; 1.0064x over previous
//
#include <hip/hip_runtime.h>

// ---------------------------------------------------------------------------
// Fused MHA forward on MI355X (gfx950), bf16 MFMA path, round 21.
// B=8, N=1024, C=1024, H=16, D=64.  M = B*N = 8192.
// ws (64 MB): [0,16M) xb then ob; [16,32M) qb then woutb; [32,48M) kb;
//             [48,64M) vbT.   d_out: [0,6M) winb (dead before out_gemm).
// NEW vs round 20 (two levers):
//  * attn T15 intra-tile pipeline: BOTH 32-key sub-tiles' QK^T MFMAs
//    hoisted to iteration top (s[0],s[1] independent) -> SM(0)+PV(0)
//    VALU work overlaps QK(1)'s MFMA drain; the MFMA->SM stall is paid
//    once per 64-key tile instead of twice. +16 VGPR (~80), no LDS/
//    barrier/staging change.
//  * cvt(x) + cvt(win) merged into ONE kernel (6 -> 5 launches; est.
//    ~8-10us/launch overhead in this harness).
// ---------------------------------------------------------------------------

typedef __bf16 bf16x8 __attribute__((ext_vector_type(8)));
typedef float f32x4 __attribute__((ext_vector_type(4)));
typedef float f32x16 __attribute__((ext_vector_type(16)));
typedef unsigned short us4v __attribute__((ext_vector_type(4)));
typedef unsigned int u32x4 __attribute__((ext_vector_type(4)));

#define MFMA16 __builtin_amdgcn_mfma_f32_16x16x32_bf16
#define MFMA32 __builtin_amdgcn_mfma_f32_32x32x16_bf16

__device__ __forceinline__ unsigned short f2bf(float f) {
    return __builtin_bit_cast(unsigned short, (__bf16)f);   // native cvt, RNE
}

__device__ __forceinline__ us4v cvt4(float4 v) {
    us4v r;
    r.x = f2bf(v.x); r.y = f2bf(v.y); r.z = f2bf(v.z); r.w = f2bf(v.w);
    return r;
}

__device__ __forceinline__ unsigned cvtpk(float lo, float hi) {
    unsigned r;
    asm volatile("v_cvt_pk_bf16_f32 %0, %1, %2" : "=v"(r) : "v"(lo), "v"(hi));
    return r;
}

// async global->LDS, 16 B per lane; LDS dest = wave-uniform base + lane*16
__device__ __forceinline__ void gl16(const unsigned short* g, unsigned short* l) {
    __builtin_amdgcn_global_load_lds(
        (const __attribute__((address_space(1))) unsigned*)g,
        (__attribute__((address_space(3))) unsigned*)l, 16, 0, 0);
}

// ---------------------------------------------------------------------------
// Kernel 0: fused fp32 -> bf16 convert for x (2097152 float4) + win (786432)
// ---------------------------------------------------------------------------
__global__ __launch_bounds__(256)
void cvt2(const float* __restrict__ x, const float* __restrict__ win,
          unsigned short* __restrict__ xb, unsigned short* __restrict__ winb) {
    const int i = blockIdx.x * 256 + threadIdx.x;
    if (i < 2097152) {
        ((us4v*)xb)[i] = cvt4(((const float4*)x)[i]);
    } else {
        const int j = i - 2097152;              // < 786432
        ((us4v*)winb)[j] = cvt4(((const float4*)win)[j]);
    }
}

// Kernel 0b: fp32 -> bf16 convert (one float4 per thread) — wout only
__global__ __launch_bounds__(256)
void cvt_bf16(const float* __restrict__ src, unsigned short* __restrict__ dst,
              int n4) {
    const int i = blockIdx.x * 256 + threadIdx.x;
    if (i < n4) {
        float4 v = ((const float4*)src)[i];
        ((us4v*)dst)[i] = cvt4(v);
    }
}

// ---------------------------------------------------------------------------
// Kernel 1: qkv = xb @ winb^T + b_in -> q (x0.125), k in (B,H,N,D) bf16,
//           V written directly transposed as vbT (B,H,D,N) bf16.
// Triple-buffered counted-vmcnt pipeline (R13; the 277us-run component).
// ---------------------------------------------------------------------------
__global__ __launch_bounds__(256, 3)
void qkv_gemm(const unsigned short* __restrict__ xb,   // (8192,1024) bf16
              const unsigned short* __restrict__ wb,   // (3072,1024) bf16
              const float* __restrict__ bias,
              unsigned short* __restrict__ qb, unsigned short* __restrict__ kb,
              unsigned short* __restrict__ vbT)
{
    __shared__ unsigned short lsa[3][128 * 32];
    __shared__ unsigned short lsb[3][128 * 32];
    const int tid  = threadIdx.x;
    const int wave = tid >> 6, lane = tid & 63;
    const int quad = lane >> 4, l15 = lane & 15;
    const int rch = (quad ^ ((l15 >> 1) & 3)) * 8;   // swizzled read chunk
    const int m0 = blockIdx.x * 128, n0 = blockIdx.y * 128;
    const int wm = (wave & 1) * 64, wn = (wave >> 1) * 64;

    const int srow = wave * 32 + (lane >> 2);
    const int scol = ((lane & 3) ^ ((lane >> 3) & 3)) * 8;   // swizzled stage
    const unsigned short* ga = xb + (size_t)(m0 + srow) * 1024 + scol;
    const unsigned short* gb = wb + (size_t)(n0 + srow) * 1024 + scol;
    const int so0 = (wave * 32) * 32;          // stage offsets within a buffer
    const int so1 = (wave * 32 + 16) * 32;

    f32x4 acc[4][4];
#pragma unroll
    for (int i = 0; i < 4; ++i)
#pragma unroll
        for (int j = 0; j < 4; ++j) acc[i][j] = (f32x4){0.f, 0.f, 0.f, 0.f};

    gl16(ga, &lsa[0][so0]);
    gl16(ga + 16 * 1024, &lsa[0][so1]);
    gl16(gb, &lsb[0][so0]);
    gl16(gb + 16 * 1024, &lsb[0][so1]);
    gl16(ga + 32, &lsa[1][so0]);
    gl16(ga + 16 * 1024 + 32, &lsa[1][so1]);
    gl16(gb + 32, &lsb[1][so0]);
    gl16(gb + 16 * 1024 + 32, &lsb[1][so1]);

    for (int kt = 0; kt < 32; ++kt) {
        const int cb = kt % 3;
        if (kt < 30) {                         // stage kt+2 (distance 2)
            const int k0 = (kt + 2) * 32;
            const int sb = (kt + 2) % 3;
            gl16(ga + k0, &lsa[sb][so0]);
            gl16(ga + 16 * 1024 + k0, &lsa[sb][so1]);
            gl16(gb + k0, &lsb[sb][so0]);
            gl16(gb + 16 * 1024 + k0, &lsb[sb][so1]);
            asm volatile("s_waitcnt vmcnt(8)" ::: "memory");
        } else if (kt == 30) {
            asm volatile("s_waitcnt vmcnt(4)" ::: "memory");
        } else {
            asm volatile("s_waitcnt vmcnt(0)" ::: "memory");
        }
        __builtin_amdgcn_s_barrier();

        const unsigned short* pa = lsa[cb];
        const unsigned short* pb = lsb[cb];
        bf16x8 af[4], bfr[4];
#pragma unroll
        for (int i = 0; i < 4; ++i)
            af[i] = *(const bf16x8*)&pa[(wm + i * 16 + l15) * 32 + rch];
#pragma unroll
        for (int j = 0; j < 4; ++j)
            bfr[j] = *(const bf16x8*)&pb[(wn + j * 16 + l15) * 32 + rch];
#pragma unroll
        for (int i = 0; i < 4; ++i)
#pragma unroll
            for (int j = 0; j < 4; ++j)
                acc[i][j] = MFMA16(af[i], bfr[j], acc[i][j], 0, 0, 0);

        asm volatile("s_waitcnt lgkmcnt(0)" ::: "memory");
        __builtin_amdgcn_sched_barrier(0);
        __builtin_amdgcn_s_barrier();
    }

    const int which = n0 >> 10;
    if (which == 2) {
        // V: write transposed (bh, d, seq); (i,r) axis is seq -> pack 4 bf16.
#pragma unroll
        for (int j = 0; j < 4; ++j) {
            const int n = n0 + wn + j * 16 + l15;
            const int c = n & 1023;
            const int h = c >> 6, d = c & 63;
            const float bv = bias[n];
#pragma unroll
            for (int i = 0; i < 4; ++i) {
                const int m = m0 + wm + i * 16 + quad * 4;   // r=0 row
                const int b = m >> 10, s = m & 1023;
                us4v pk;
#pragma unroll
                for (int r = 0; r < 4; ++r) pk[r] = f2bf(acc[i][j][r] + bv);
                *(us4v*)&vbT[(size_t)((b * 16 + h) * 64 + d) * 1024 + s] = pk;
            }
        }
    } else {
        unsigned short* __restrict__ dst = (which == 0) ? qb : kb;
        const float sc = (which == 0) ? 0.125f : 1.0f;   // q / sqrt(64)
#pragma unroll
        for (int j = 0; j < 4; ++j) {
            const int n = n0 + wn + j * 16 + l15;
            const int c = n & 1023;
            const int h = c >> 6, d = c & 63;
            const float bv = bias[n];
#pragma unroll
            for (int i = 0; i < 4; ++i)
#pragma unroll
                for (int r = 0; r < 4; ++r) {
                    const int m = m0 + wm + i * 16 + quad * 4 + r;
                    const int b = m >> 10, s = m & 1023;
                    const float v = (acc[i][j][r] + bv) * sc;
                    dst[(size_t)((b * 16 + h) * 1024 + s) * 64 + d] = f2bf(v);
                }
        }
    }
}

// ---------------------------------------------------------------------------
// Kernel 2: flash attention, 32x32 MFMA, in-register P (T12) + T15 pipeline.
//   Both sub-tiles' QK^T hoisted before softmax: SM/PV of sub0 overlap
//   QK(sub1) MFMA drain. Raw mask as MFMA C-operand; p = __expf(s).
// launch_bounds(256,3): ~80 VGPR, no spill. Grid 1024, XCD-swizzled.
// ---------------------------------------------------------------------------
__global__ __launch_bounds__(256, 3)
void attn_kernel(const unsigned short* __restrict__ qb,
                 const unsigned short* __restrict__ kb,
                 const unsigned short* __restrict__ vbT,  // (bh, d, n)
                 const float* __restrict__ mask,          // raw (1024,1024)
                 unsigned short* __restrict__ ob)   // (B, N, C) bf16
{
    __shared__ unsigned short lsk[2][2][64 * 32];  // [buf][d-half][key*32]
    __shared__ unsigned short lsv[2][2][64 * 32];  // [buf][key-half][d*32]
    const int tid  = threadIdx.x;
    const int wave = tid >> 6, lane = tid & 63;
    const int r5 = lane & 31, hl = lane >> 5;
    const int rs = ((r5 >> 1) ^ (r5 >> 3)) & 3;    // read-chunk swizzle
    const int p  = blockIdx.x;
    const int lg = (p & 7) * 128 + (p >> 3);       // XCD swizzle (bijective)
    const int bh = lg >> 3;                        // b*16+h
    const int q0 = (lg & 7) * 128;
    const int b = bh >> 4, head = bh & 15;

    const unsigned short* __restrict__ kbase = kb + (size_t)bh * 65536;
    const unsigned short* __restrict__ vtb  = vbT + (size_t)bh * 65536;

    // stage: row r = wave*16 + lane>>2; S(r)=((r>>1)^(r>>3))&3 via lane bits
    const int scol =
        ((lane & 3) ^ ((lane >> 3) & 3) ^ ((2 * wave + (lane >> 5)) & 3)) * 8;
    const unsigned short* gk = kbase + (size_t)(wave * 16 + (lane >> 2)) * 64
                                     + scol;
    const unsigned short* gv = vtb + (size_t)(wave * 16 + (lane >> 2)) * 1024
                                   + scol;
    const int so = (wave * 16) * 32;             // stage offset within a half

    // Q fragments (B-operand: n=q=l&31, k=d=kk*16+8*hl+j), q pre-scaled
    const int q = q0 + wave * 32 + r5;
    bf16x8 bq[4];
    {
        const unsigned short* qrow = qb + (size_t)(bh * 1024 + q) * 64;
#pragma unroll
        for (int kk = 0; kk < 4; ++kk)
            bq[kk] = *(const bf16x8*)(qrow + kk * 16 + hl * 8);
    }

    float lsum = 0.f;
    f32x16 acc[2];                 // [dt]: O^T[d=32dt+(r&3)+8(r>>2)+4hl][q]
#pragma unroll
    for (int dt = 0; dt < 2; ++dt)
#pragma unroll
        for (int r = 0; r < 16; ++r) acc[dt][r] = 0.f;

    const float* __restrict__ mq = mask + (size_t)q * 1024;

    // prologue: stage tile 0 into buf 0
    gl16(gk, &lsk[0][0][so]);
    gl16(gk + 32, &lsk[0][1][so]);
    gl16(gv, &lsv[0][0][so]);
    gl16(gv + 32, &lsv[0][1][so]);
    __syncthreads();

    int buf = 0;
    for (int kt = 0; kt < 16; ++kt) {
        // masks for CURRENT tile (oldest vmem -> QK's wait leaves the
        // younger prefetch gl16s in flight)
        f32x16 msk[2];
#pragma unroll
        for (int t32 = 0; t32 < 2; ++t32)
#pragma unroll
            for (int oct = 0; oct < 4; ++oct) {
                const float4 mv = *(const float4*)
                    &mq[kt * 64 + t32 * 32 + oct * 8 + hl * 4];
                msk[t32][4 * oct + 0] = mv.x;
                msk[t32][4 * oct + 1] = mv.y;
                msk[t32][4 * oct + 2] = mv.z;
                msk[t32][4 * oct + 3] = mv.w;
            }
        __builtin_amdgcn_sched_barrier(0);     // keep mask loads oldest
        if (kt < 15) {                         // stage next tile early
            gl16(gk + (size_t)(kt + 1) * 4096, &lsk[buf ^ 1][0][so]);
            gl16(gk + (size_t)(kt + 1) * 4096 + 32, &lsk[buf ^ 1][1][so]);
            gl16(gv + (size_t)(kt + 1) * 64, &lsv[buf ^ 1][0][so]);
            gl16(gv + (size_t)(kt + 1) * 64 + 32, &lsv[buf ^ 1][1][so]);
        }

        // T15: QK^T for BOTH 32-key sub-tiles first. SM/PV of sub 0 then
        // run on the VALU while sub 1's MFMAs are still draining.
        f32x16 s[2];
        __builtin_amdgcn_s_setprio(1);
#pragma unroll
        for (int t32 = 0; t32 < 2; ++t32) {
            s[t32] = msk[t32];
#pragma unroll
            for (int kk = 0; kk < 4; ++kk) {
                const unsigned short* kp = lsk[buf][kk >> 1];
                const int c4 = 2 * (kk & 1) + hl;
                const bf16x8 ka = *(const bf16x8*)
                    &kp[(t32 * 32 + r5) * 32 + ((c4 ^ rs) * 8)];
                s[t32] = MFMA32(ka, bq[kk], s[t32], 0, 0, 0);
            }
        }
        __builtin_amdgcn_s_setprio(0);

#pragma unroll
        for (int t32 = 0; t32 < 2; ++t32) {
            // softmax: p = exp(s); pack + permlane32_swap -> B-frags
            float pv[16];
            float ts = 0.f;
#pragma unroll
            for (int r = 0; r < 16; ++r) {
                pv[r] = __expf(s[t32][r]);
                ts += pv[r];
            }
            lsum += ts;

            bf16x8 pfr[2];
#pragma unroll
            for (int cl = 0; cl < 2; ++cl) {
                unsigned xa = cvtpk(pv[8 * cl + 0], pv[8 * cl + 1]);
                unsigned xb = cvtpk(pv[8 * cl + 2], pv[8 * cl + 3]);
                unsigned ya = cvtpk(pv[8 * cl + 4], pv[8 * cl + 5]);
                unsigned yb = cvtpk(pv[8 * cl + 6], pv[8 * cl + 7]);
                asm volatile("v_permlane32_swap_b32 %0, %1"
                             : "+v"(xa), "+v"(ya));
                asm volatile("v_permlane32_swap_b32 %0, %1"
                             : "+v"(xb), "+v"(yb));
                const u32x4 t = {xa, xb, ya, yb};
                pfr[cl] = __builtin_bit_cast(bf16x8, t);
            }

            // O^T += V^T x P^T  (A = V^T frag, B = P frag), K=16 per chunk
            __builtin_amdgcn_s_setprio(1);
#pragma unroll
            for (int cl = 0; cl < 2; ++cl) {
                const int cg = t32 * 2 + cl;
                const unsigned short* vp = lsv[buf][cg >> 1];
                const int c4v = 2 * (cg & 1) + hl;
                const int voff = (c4v ^ rs) * 8;
#pragma unroll
                for (int dt = 0; dt < 2; ++dt) {
                    const bf16x8 va = *(const bf16x8*)
                        &vp[(dt * 32 + r5) * 32 + voff];
                    acc[dt] = MFMA32(va, pfr[cl], acc[dt], 0, 0, 0);
                }
            }
            __builtin_amdgcn_s_setprio(0);
        }

        __syncthreads();                       // drain stage + protect bufs
        buf ^= 1;
    }

    // lane covers keys with (key&7)>>2 == hl; partner lane has the rest
    lsum += __shfl_xor(lsum, 32, 64);
    const float inv = 1.0f / lsum;

    unsigned short* orow =
        ob + (size_t)(b * 1024 + q) * 1024 + head * 64;
#pragma unroll
    for (int dt = 0; dt < 2; ++dt)
#pragma unroll
        for (int oct = 0; oct < 4; ++oct) {
            us4v o;
#pragma unroll
            for (int r = 0; r < 4; ++r)
                o[r] = f2bf(acc[dt][4 * oct + r] * inv);
            *(us4v*)&orow[dt * 32 + oct * 8 + hl * 4] = o;
        }
}

// ---------------------------------------------------------------------------
// Kernel 3: out = ob(bf16) @ woutb^T + out_b, fp32 to d_out (R13 unchanged).
// ---------------------------------------------------------------------------
__global__ __launch_bounds__(256, 3)
void out_gemm(const unsigned short* __restrict__ a,   // (8192,1024) bf16
              const unsigned short* __restrict__ wb,  // (1024,1024) bf16
              const float* __restrict__ bias, float* __restrict__ out)
{
    __shared__ unsigned short lsa[3][128 * 32];
    __shared__ unsigned short lsb[3][128 * 32];
    const int tid  = threadIdx.x;
    const int wave = tid >> 6, lane = tid & 63;
    const int quad = lane >> 4, l15 = lane & 15;
    const int rch = (quad ^ ((l15 >> 1) & 3)) * 8;
    const int m0 = blockIdx.x * 128, n0 = blockIdx.y * 128;
    const int wm = (wave & 1) * 64, wn = (wave >> 1) * 64;

    const int srow = wave * 32 + (lane >> 2);
    const int scol = ((lane & 3) ^ ((lane >> 3) & 3)) * 8;
    const unsigned short* ga = a + (size_t)(m0 + srow) * 1024 + scol;
    const unsigned short* gb = wb + (size_t)(n0 + srow) * 1024 + scol;
    const int so0 = (wave * 32) * 32;
    const int so1 = (wave * 32 + 16) * 32;

    f32x4 acc[4][4];
#pragma unroll
    for (int i = 0; i < 4; ++i)
#pragma unroll
        for (int j = 0; j < 4; ++j) acc[i][j] = (f32x4){0.f, 0.f, 0.f, 0.f};

    gl16(ga, &lsa[0][so0]);
    gl16(ga + 16 * 1024, &lsa[0][so1]);
    gl16(gb, &lsb[0][so0]);
    gl16(gb + 16 * 1024, &lsb[0][so1]);
    gl16(ga + 32, &lsa[1][so0]);
    gl16(ga + 16 * 1024 + 32, &lsa[1][so1]);
    gl16(gb + 32, &lsb[1][so0]);
    gl16(gb + 16 * 1024 + 32, &lsb[1][so1]);

    for (int kt = 0; kt < 32; ++kt) {
        const int cb = kt % 3;
        if (kt < 30) {
            const int k0 = (kt + 2) * 32;
            const int sb = (kt + 2) % 3;
            gl16(ga + k0, &lsa[sb][so0]);
            gl16(ga + 16 * 1024 + k0, &lsa[sb][so1]);
            gl16(gb + k0, &lsb[sb][so0]);
            gl16(gb + 16 * 1024 + k0, &lsb[sb][so1]);
            asm volatile("s_waitcnt vmcnt(8)" ::: "memory");
        } else if (kt == 30) {
            asm volatile("s_waitcnt vmcnt(4)" ::: "memory");
        } else {
            asm volatile("s_waitcnt vmcnt(0)" ::: "memory");
        }
        __builtin_amdgcn_s_barrier();

        const unsigned short* pa = lsa[cb];
        const unsigned short* pb = lsb[cb];
        bf16x8 af[4], bfr[4];
#pragma unroll
        for (int i = 0; i < 4; ++i)
            af[i] = *(const bf16x8*)&pa[(wm + i * 16 + l15) * 32 + rch];
#pragma unroll
        for (int j = 0; j < 4; ++j)
            bfr[j] = *(const bf16x8*)&pb[(wn + j * 16 + l15) * 32 + rch];
#pragma unroll
        for (int i = 0; i < 4; ++i)
#pragma unroll
            for (int j = 0; j < 4; ++j)
                acc[i][j] = MFMA16(af[i], bfr[j], acc[i][j], 0, 0, 0);

        asm volatile("s_waitcnt lgkmcnt(0)" ::: "memory");
        __builtin_amdgcn_sched_barrier(0);
        __builtin_amdgcn_s_barrier();
    }

#pragma unroll
    for (int j = 0; j < 4; ++j) {
        const int n = n0 + wn + j * 16 + l15;
        const float bv = bias[n];
#pragma unroll
        for (int i = 0; i < 4; ++i)
#pragma unroll
            for (int r = 0; r < 4; ++r) {
                const int m = m0 + wm + i * 16 + quad * 4 + r;
                out[(size_t)m * 1024 + n] = acc[i][j][r] + bv;
            }
    }
}

// ---------------------------------------------------------------------------
extern "C" void kernel_launch(void* const* d_in, const int* in_sizes, int n_in,
                              void* d_out, int out_size, void* d_ws, size_t ws_size,
                              hipStream_t stream) {
    const float* x    = (const float*)d_in[0];   // (8, 1024, 1024)
    const float* mask = (const float*)d_in[1];   // (1024, 1024)
    const float* win  = (const float*)d_in[2];   // (3072, 1024)
    const float* bin  = (const float*)d_in[3];   // (3072)
    const float* wout = (const float*)d_in[4];   // (1024, 1024)
    const float* bout = (const float*)d_in[5];   // (1024)
    float* out = (float*)d_out;                  // (8, 1024, 1024)

    char* ws = (char*)d_ws;
    unsigned short* xb = (unsigned short*)(ws);
    unsigned short* ob = (unsigned short*)(ws);                       // overlays xb
    unsigned short* qb = (unsigned short*)(ws + (size_t)(16 << 20));
    unsigned short* kb = (unsigned short*)(ws + (size_t)(32 << 20));
    unsigned short* vbT = (unsigned short*)(ws + (size_t)(48 << 20));
    unsigned short* winb  = (unsigned short*)d_out;                   // [0, 6M)
    unsigned short* woutb = qb;   // overlays qb AFTER attn (qb dead) — no race

    cvt2<<<dim3(11264), 256, 0, stream>>>(x, win, xb, winb);
    qkv_gemm<<<dim3(64, 24), 256, 0, stream>>>(xb, winb, bin, qb, kb, vbT);
    attn_kernel<<<dim3(1024), 256, 0, stream>>>(qb, kb, vbT, mask, ob);
    cvt_bf16<<<dim3(1024), 256, 0, stream>>>(wout, woutb, 1024 * 1024 / 4);
    out_gemm<<<dim3(64, 8), 256, 0, stream>>>(ob, woutb, bout, out);
}